// Round 5
// baseline (189.828 us; speedup 1.0000x reference)
//
#include <hip/hip_runtime.h>

#define N_NODES 100000
#define N_EDGES 1600000
#define D 64

// ---- fine buckets: 32 nodes each, 100000/32 = 3125 exactly ----
#define FSHIFT 5
#define FNODES 32
#define NFB 3125
#define CAPF 800            // mean 512, sigma ~22.6 -> +12.7 sigma

// ---- coarse buckets: 2048 nodes each ----
#define CSHIFT 11
#define NCB 49              // ceil(100000/2048)
#define CCAP 36864          // 9*4096; mean 32768, sigma ~179 -> +22 sigma
#define FPC 64              // fine buckets per coarse (2048/32)
#define NCHUNKB 9           // CCAP / 4096

#define CHUNK 4096
#define EPT 16
#define NCHUNKA 391         // ceil(1600000/4096)

#define COLBITS 17
#define COLMASK 0x1FFFF

// ws layout (bytes)
#define FCUR_OFF   0           // int[NFB]  fine cursors (init f*CAPF)
#define CCUR_OFF   16384       // int[NCB]  coarse cursors (init c*CCAP)
#define CPAIRS_OFF 32768       // int[NCB*CCAP]  (rl11<<17|col)    7,225,344 B
#define FPAIRS_OFF 7258112     // int[NFB*CAPF]  (rl5<<17|col)    10,000,000 B
#define Y_OFF      17258112    // ushort[N_NODES*D] bf16 y        12,800,000 B

__device__ __forceinline__ float bf2f(unsigned short u) {
    return __uint_as_float(((unsigned)u) << 16);
}
__device__ __forceinline__ unsigned f2bf(float f) {
    unsigned bits = __float_as_uint(f);
    return (bits + 0x7FFFu + ((bits >> 16) & 1u)) >> 16;
}

__global__ void initcur_kernel(int* __restrict__ fcur, int* __restrict__ ccur) {
    int i = blockIdx.x * blockDim.x + threadIdx.x;
    if (i < NFB) fcur[i] = i * CAPF;
    if (i < NCB) ccur[i] = i * CCAP;
}

// Pass A: bucket edges by row>>11 into 49 coarse regions (runs ~84 edges).
__global__ __launch_bounds__(256) void scatA_kernel(const int* __restrict__ row,
                                                    const int* __restrict__ col,
                                                    int* __restrict__ ccur,
                                                    int* __restrict__ cpairs) {
    __shared__ int lcnt[NCB];
    int t = threadIdx.x;
    int base = blockIdx.x * CHUNK;
    if (t < NCB) lcnt[t] = 0;
    __syncthreads();
    int r[EPT], c[EPT], pos[EPT];
#pragma unroll
    for (int i = 0; i < EPT; ++i) {
        int e = base + i * 256 + t;
        if (e < N_EDGES) {
            r[i] = row[e];
            c[i] = col[e];
            pos[i] = atomicAdd(&lcnt[r[i] >> CSHIFT], 1);
        } else r[i] = -1;
    }
    __syncthreads();
    if (t < NCB) {
        int cc = lcnt[t];
        if (cc) lcnt[t] = atomicAdd(&ccur[t], cc);
    }
    __syncthreads();
#pragma unroll
    for (int i = 0; i < EPT; ++i) {
        if (r[i] >= 0) {
            int cb = r[i] >> CSHIFT;
            int rl = r[i] & ((1 << CSHIFT) - 1);   // 11-bit local row
            cpairs[lcnt[cb] + pos[i]] = (rl << COLBITS) | c[i];
        }
    }
}

// Pass B: refine one coarse chunk into its 64 fine buckets (runs ~64 edges).
__global__ __launch_bounds__(256) void scatB_kernel(const int* __restrict__ cpairs,
                                                    const int* __restrict__ ccur,
                                                    int* __restrict__ fcur,
                                                    int* __restrict__ fpairs) {
    __shared__ int lcnt[FPC];
    int t = threadIdx.x;
    int cb = blockIdx.x / NCHUNKB;
    int k  = blockIdx.x % NCHUNKB;
    int beg = cb * CCAP + k * CHUNK;
    int end = ccur[cb];                 // end cursor after pass A
    if (end > beg + CHUNK) end = beg + CHUNK;
    if (t < FPC) lcnt[t] = 0;
    __syncthreads();
    int pc[EPT], pos[EPT];
#pragma unroll
    for (int i = 0; i < EPT; ++i) {
        int e = beg + i * 256 + t;
        if (e < end) {
            pc[i] = cpairs[e];
            pos[i] = atomicAdd(&lcnt[pc[i] >> (COLBITS + FSHIFT)], 1);
        } else pc[i] = -1;
    }
    __syncthreads();
    if (t < FPC) {
        int cc = lcnt[t];
        if (cc) lcnt[t] = atomicAdd(&fcur[(cb << 6) + t], cc);
    }
    __syncthreads();
#pragma unroll
    for (int i = 0; i < EPT; ++i) {
        if (pc[i] >= 0) {
            int fl = pc[i] >> (COLBITS + FSHIFT);           // fine-local 0..63
            int rl5 = (pc[i] >> COLBITS) & (FNODES - 1);
            fpairs[lcnt[fl] + pos[i]] = (rl5 << COLBITS) | (pc[i] & COLMASK);
        }
    }
}

// Per 64 nodes (two fine buckets): degree hist -> dinv -> y = bf16(dinv * x@W^T)
// 4x4 register tiles, XT/WT staged d-major in LDS, float4 reads.
__global__ __launch_bounds__(256) void xform_kernel(
        const float* __restrict__ x, const float* __restrict__ W,
        const int* __restrict__ fpairs, const int* __restrict__ fcur,
        unsigned short* __restrict__ y) {
    __shared__ __align__(16) float XT[D * 68];   // XT[d*68 + n]
    __shared__ __align__(16) float WT[D * 68];   // WT[d*68 + j]
    __shared__ int hist[64];
    __shared__ float dl[64];
    int t = threadIdx.x;
    int b = blockIdx.x;
    int nb0 = b << 6;                  // 64 nodes per block
    for (int i = t; i < D * D; i += 256) {
        int j = i >> 6, d = i & 63;
        WT[d * 68 + j] = W[i];
    }
    if (t < 64) hist[t] = 0;
    __syncthreads();
    for (int i = t; i < 64 * D; i += 256) {
        int n = i >> 6, d = i & 63;
        int g = nb0 + n;
        XT[d * 68 + n] = (g < N_NODES) ? x[(size_t)g * D + d] : 0.0f;
    }
#pragma unroll
    for (int half = 0; half < 2; ++half) {
        int f = 2 * b + half;
        if (f < NFB) {
            int beg = f * CAPF, end = fcur[f];
            for (int k = beg + t; k < end; k += 256)
                atomicAdd(&hist[(fpairs[k] >> COLBITS) + (half << FSHIFT)], 1);
        }
    }
    __syncthreads();
    if (t < 64) dl[t] = (hist[t] > 0) ? rsqrtf((float)hist[t]) : 0.0f;
    __syncthreads();
    int tj = t & 15, tn = t >> 4;      // 16 j-tiles x 16 n-tiles
    float4 a0 = {0,0,0,0}, a1 = {0,0,0,0}, a2 = {0,0,0,0}, a3 = {0,0,0,0};
#pragma unroll 8
    for (int d = 0; d < D; ++d) {
        float4 xv = *(const float4*)&XT[d * 68 + tn * 4];
        float4 wv = *(const float4*)&WT[d * 68 + tj * 4];
        a0.x = fmaf(xv.x, wv.x, a0.x); a0.y = fmaf(xv.x, wv.y, a0.y);
        a0.z = fmaf(xv.x, wv.z, a0.z); a0.w = fmaf(xv.x, wv.w, a0.w);
        a1.x = fmaf(xv.y, wv.x, a1.x); a1.y = fmaf(xv.y, wv.y, a1.y);
        a1.z = fmaf(xv.y, wv.z, a1.z); a1.w = fmaf(xv.y, wv.w, a1.w);
        a2.x = fmaf(xv.z, wv.x, a2.x); a2.y = fmaf(xv.z, wv.y, a2.y);
        a2.z = fmaf(xv.z, wv.z, a2.z); a2.w = fmaf(xv.z, wv.w, a2.w);
        a3.x = fmaf(xv.w, wv.x, a3.x); a3.y = fmaf(xv.w, wv.y, a3.y);
        a3.z = fmaf(xv.w, wv.z, a3.z); a3.w = fmaf(xv.w, wv.w, a3.w);
    }
    int jb = tj * 4;
#pragma unroll
    for (int s = 0; s < 4; ++s) {
        int g = nb0 + tn * 4 + s;
        if (g < N_NODES) {
            float sc = dl[tn * 4 + s];
            float4 a = (s == 0) ? a0 : (s == 1) ? a1 : (s == 2) ? a2 : a3;
            unsigned lo = f2bf(a.x * sc) | (f2bf(a.y * sc) << 16);
            unsigned hi = f2bf(a.z * sc) | (f2bf(a.w * sc) << 16);
            *(uint2*)(y + (size_t)g * D + jb) = make_uint2(lo, hi);
        }
    }
}

// Per fine bucket (32 nodes): LDS hist -> scan -> fine-bin -> per-wave gather.
__global__ __launch_bounds__(256) void mega_kernel(
        const int* __restrict__ fpairs, const int* __restrict__ fcur,
        const unsigned short* __restrict__ y,
        const float* __restrict__ bias, float* __restrict__ out) {
    __shared__ int hist[FNODES];
    __shared__ int sc[FNODES];
    __shared__ int lrptr[FNODES + 1];
    __shared__ int lcur[FNODES];
    __shared__ float dl[FNODES];
    __shared__ int lds_scol[CAPF];
    int t = threadIdx.x;
    int b = blockIdx.x;
    int beg = b * CAPF, end = fcur[b];
    if (t < FNODES) hist[t] = 0;
    __syncthreads();
    for (int k = beg + t; k < end; k += 256)
        atomicAdd(&hist[fpairs[k] >> COLBITS], 1);
    __syncthreads();
    if (t < FNODES) sc[t] = hist[t];
    __syncthreads();
    for (int off = 1; off < FNODES; off <<= 1) {
        int v = (t < FNODES && t >= off) ? sc[t - off] : 0;
        __syncthreads();
        if (t < FNODES) sc[t] += v;
        __syncthreads();
    }
    if (t < FNODES) {
        lrptr[t + 1] = sc[t];
        lcur[t] = sc[t] - hist[t];
        dl[t] = (hist[t] > 0) ? rsqrtf((float)hist[t]) : 0.0f;
    }
    if (t == 0) lrptr[0] = 0;
    __syncthreads();
    for (int k = beg + t; k < end; k += 256) {
        int p = fpairs[k];
        int pos = atomicAdd(&lcur[p >> COLBITS], 1);
        lds_scol[pos] = p & COLMASK;
    }
    __syncthreads();
    int wave = t >> 6, j = t & 63;
    float bj = bias[j];
    for (int ln = wave; ln < FNODES; ln += 4) {
        int s = lrptr[ln], e2 = lrptr[ln + 1];
        float a0 = 0, a1 = 0, a2 = 0, a3 = 0, a4 = 0, a5 = 0, a6 = 0, a7 = 0;
        int k = s;
        for (; k + 7 < e2; k += 8) {
            int c0 = lds_scol[k + 0], c1 = lds_scol[k + 1];
            int c2 = lds_scol[k + 2], c3 = lds_scol[k + 3];
            int c4 = lds_scol[k + 4], c5 = lds_scol[k + 5];
            int c6 = lds_scol[k + 6], c7 = lds_scol[k + 7];
            a0 += bf2f(y[(size_t)c0 * D + j]);
            a1 += bf2f(y[(size_t)c1 * D + j]);
            a2 += bf2f(y[(size_t)c2 * D + j]);
            a3 += bf2f(y[(size_t)c3 * D + j]);
            a4 += bf2f(y[(size_t)c4 * D + j]);
            a5 += bf2f(y[(size_t)c5 * D + j]);
            a6 += bf2f(y[(size_t)c6 * D + j]);
            a7 += bf2f(y[(size_t)c7 * D + j]);
        }
        for (; k < e2; ++k) a0 += bf2f(y[(size_t)lds_scol[k] * D + j]);
        float sum = ((a0 + a1) + (a2 + a3)) + ((a4 + a5) + (a6 + a7));
        int n = (b << FSHIFT) + ln;
        out[(size_t)n * D + j] = fmaxf(fmaf(dl[ln], sum, bj), 0.0f);
    }
}

extern "C" void kernel_launch(void* const* d_in, const int* in_sizes, int n_in,
                              void* d_out, int out_size, void* d_ws, size_t ws_size,
                              hipStream_t stream) {
    const float* x    = (const float*)d_in[0];
    const int*   eidx = (const int*)d_in[1];
    const float* W    = (const float*)d_in[2];
    const float* b    = (const float*)d_in[3];
    float* out = (float*)d_out;
    char* ws = (char*)d_ws;

    const int* row = eidx;
    const int* col = eidx + N_EDGES;

    int* fcur   = (int*)(ws + FCUR_OFF);
    int* ccur   = (int*)(ws + CCUR_OFF);
    int* cpairs = (int*)(ws + CPAIRS_OFF);
    int* fpairs = (int*)(ws + FPAIRS_OFF);
    unsigned short* y = (unsigned short*)(ws + Y_OFF);

    initcur_kernel<<<(NFB + 255) / 256, 256, 0, stream>>>(fcur, ccur);
    scatA_kernel<<<NCHUNKA, 256, 0, stream>>>(row, col, ccur, cpairs);
    scatB_kernel<<<NCB * NCHUNKB, 256, 0, stream>>>(cpairs, ccur, fcur, fpairs);
    xform_kernel<<<(N_NODES + 63) / 64, 256, 0, stream>>>(x, W, fpairs, fcur, y);
    mega_kernel<<<NFB, 256, 0, stream>>>(fpairs, fcur, y, b, out);
}

// Round 7
// 183.814 us; speedup vs baseline: 1.0327x; 1.0327x over previous
//
#include <hip/hip_runtime.h>

#define N_NODES 100000
#define N_EDGES 1600000
#define D 64

// ---- fine buckets: 32 nodes each, 100000/32 = 3125 exactly ----
#define FSHIFT 5
#define FNODES 32
#define NFB 3125
#define CAPF 800            // mean 512, sigma ~22.6 -> +12.7 sigma

// ---- coarse buckets: 2048 nodes each ----
#define CSHIFT 11
#define NCB 49              // ceil(100000/2048)
#define CCAP 36864          // 9*4096; mean 32768, sigma ~179 -> +22 sigma
#define FPC 64              // fine buckets per coarse (2048/32)
#define NCHUNKB 9           // CCAP / 4096

#define CHUNK 4096
#define EPT 16
#define NCHUNKA 391         // ceil(1600000/4096)

#define COLBITS 17
#define COLMASK 0x1FFFF

// ws layout (bytes)
#define FCUR_OFF   0           // int[NFB]  fine cursors (init f*CAPF)
#define CCUR_OFF   16384       // int[NCB]  coarse cursors (init c*CCAP)
#define CPAIRS_OFF 32768       // int[NCB*CCAP]  (rl11<<17|col)    7,225,344 B
#define FPAIRS_OFF 7258112     // int[NFB*CAPF]  (rl5<<17|col)    10,000,000 B
#define Y_OFF      17258112    // ushort[N_NODES*D] bf16 y        12,800,000 B

typedef float fvec4 __attribute__((ext_vector_type(4)));

__device__ __forceinline__ float bf2f(unsigned short u) {
    return __uint_as_float(((unsigned)u) << 16);
}
__device__ __forceinline__ unsigned f2bf(float f) {
    unsigned bits = __float_as_uint(f);
    return (bits + 0x7FFFu + ((bits >> 16) & 1u)) >> 16;
}

__global__ void initcur_kernel(int* __restrict__ fcur, int* __restrict__ ccur) {
    int i = blockIdx.x * blockDim.x + threadIdx.x;
    if (i < NFB) fcur[i] = i * CAPF;
    if (i < NCB) ccur[i] = i * CCAP;
}

// Pass A: bucket edges by row>>11 into 49 coarse regions (runs ~84 edges).
__global__ __launch_bounds__(256) void scatA_kernel(const int* __restrict__ row,
                                                    const int* __restrict__ col,
                                                    int* __restrict__ ccur,
                                                    int* __restrict__ cpairs) {
    __shared__ int lcnt[NCB];
    int t = threadIdx.x;
    int base = blockIdx.x * CHUNK;
    if (t < NCB) lcnt[t] = 0;
    __syncthreads();
    int r[EPT], c[EPT], pos[EPT];
#pragma unroll
    for (int i = 0; i < EPT; ++i) {
        int e = base + i * 256 + t;
        if (e < N_EDGES) {
            r[i] = row[e];
            c[i] = col[e];
            pos[i] = atomicAdd(&lcnt[r[i] >> CSHIFT], 1);
        } else r[i] = -1;
    }
    __syncthreads();
    if (t < NCB) {
        int cc = lcnt[t];
        if (cc) lcnt[t] = atomicAdd(&ccur[t], cc);
    }
    __syncthreads();
#pragma unroll
    for (int i = 0; i < EPT; ++i) {
        if (r[i] >= 0) {
            int cb = r[i] >> CSHIFT;
            int rl = r[i] & ((1 << CSHIFT) - 1);   // 11-bit local row
            cpairs[lcnt[cb] + pos[i]] = (rl << COLBITS) | c[i];
        }
    }
}

// Pass B: refine one coarse chunk into its 64 fine buckets (runs ~64 edges).
__global__ __launch_bounds__(256) void scatB_kernel(const int* __restrict__ cpairs,
                                                    const int* __restrict__ ccur,
                                                    int* __restrict__ fcur,
                                                    int* __restrict__ fpairs) {
    __shared__ int lcnt[FPC];
    int t = threadIdx.x;
    int cb = blockIdx.x / NCHUNKB;
    int k  = blockIdx.x % NCHUNKB;
    int beg = cb * CCAP + k * CHUNK;
    int end = ccur[cb];                 // end cursor after pass A
    if (end > beg + CHUNK) end = beg + CHUNK;
    if (t < FPC) lcnt[t] = 0;
    __syncthreads();
    int pc[EPT], pos[EPT];
#pragma unroll
    for (int i = 0; i < EPT; ++i) {
        int e = beg + i * 256 + t;
        if (e < end) {
            pc[i] = cpairs[e];
            pos[i] = atomicAdd(&lcnt[pc[i] >> (COLBITS + FSHIFT)], 1);
        } else pc[i] = -1;
    }
    __syncthreads();
    if (t < FPC) {
        int cc = lcnt[t];
        if (cc) lcnt[t] = atomicAdd(&fcur[(cb << 6) + t], cc);
    }
    __syncthreads();
#pragma unroll
    for (int i = 0; i < EPT; ++i) {
        if (pc[i] >= 0) {
            int fl = pc[i] >> (COLBITS + FSHIFT);           // fine-local 0..63
            int rl5 = (pc[i] >> COLBITS) & (FNODES - 1);
            fpairs[lcnt[fl] + pos[i]] = (rl5 << COLBITS) | (pc[i] & COLMASK);
        }
    }
}

// Per 64 nodes (two fine buckets): degree hist -> dinv -> y = bf16(dinv * x@W^T)
// 4x4 register tiles, XT/WT staged d-major in LDS, float4 reads.
__global__ __launch_bounds__(256) void xform_kernel(
        const float* __restrict__ x, const float* __restrict__ W,
        const int* __restrict__ fpairs, const int* __restrict__ fcur,
        unsigned short* __restrict__ y) {
    __shared__ __align__(16) float XT[D * 68];   // XT[d*68 + n]
    __shared__ __align__(16) float WT[D * 68];   // WT[d*68 + j]
    __shared__ int hist[64];
    __shared__ float dl[64];
    int t = threadIdx.x;
    int b = blockIdx.x;
    int nb0 = b << 6;                  // 64 nodes per block
    for (int i = t; i < D * D; i += 256) {
        int j = i >> 6, d = i & 63;
        WT[d * 68 + j] = W[i];
    }
    if (t < 64) hist[t] = 0;
    __syncthreads();
    for (int i = t; i < 64 * D; i += 256) {
        int n = i >> 6, d = i & 63;
        int g = nb0 + n;
        XT[d * 68 + n] = (g < N_NODES) ? x[(size_t)g * D + d] : 0.0f;
    }
#pragma unroll
    for (int half = 0; half < 2; ++half) {
        int f = 2 * b + half;
        if (f < NFB) {
            int beg = f * CAPF, end = fcur[f];
            for (int k = beg + t; k < end; k += 256)
                atomicAdd(&hist[(fpairs[k] >> COLBITS) + (half << FSHIFT)], 1);
        }
    }
    __syncthreads();
    if (t < 64) dl[t] = (hist[t] > 0) ? rsqrtf((float)hist[t]) : 0.0f;
    __syncthreads();
    int tj = t & 15, tn = t >> 4;      // 16 j-tiles x 16 n-tiles
    float4 a0 = {0,0,0,0}, a1 = {0,0,0,0}, a2 = {0,0,0,0}, a3 = {0,0,0,0};
#pragma unroll 8
    for (int d = 0; d < D; ++d) {
        float4 xv = *(const float4*)&XT[d * 68 + tn * 4];
        float4 wv = *(const float4*)&WT[d * 68 + tj * 4];
        a0.x = fmaf(xv.x, wv.x, a0.x); a0.y = fmaf(xv.x, wv.y, a0.y);
        a0.z = fmaf(xv.x, wv.z, a0.z); a0.w = fmaf(xv.x, wv.w, a0.w);
        a1.x = fmaf(xv.y, wv.x, a1.x); a1.y = fmaf(xv.y, wv.y, a1.y);
        a1.z = fmaf(xv.y, wv.z, a1.z); a1.w = fmaf(xv.y, wv.w, a1.w);
        a2.x = fmaf(xv.z, wv.x, a2.x); a2.y = fmaf(xv.z, wv.y, a2.y);
        a2.z = fmaf(xv.z, wv.z, a2.z); a2.w = fmaf(xv.z, wv.w, a2.w);
        a3.x = fmaf(xv.w, wv.x, a3.x); a3.y = fmaf(xv.w, wv.y, a3.y);
        a3.z = fmaf(xv.w, wv.z, a3.z); a3.w = fmaf(xv.w, wv.w, a3.w);
    }
    int jb = tj * 4;
#pragma unroll
    for (int s = 0; s < 4; ++s) {
        int g = nb0 + tn * 4 + s;
        if (g < N_NODES) {
            float sc = dl[tn * 4 + s];
            float4 a = (s == 0) ? a0 : (s == 1) ? a1 : (s == 2) ? a2 : a3;
            unsigned lo = f2bf(a.x * sc) | (f2bf(a.y * sc) << 16);
            unsigned hi = f2bf(a.z * sc) | (f2bf(a.w * sc) << 16);
            *(uint2*)(y + (size_t)g * D + jb) = make_uint2(lo, hi);
        }
    }
}

// Per fine bucket (32 nodes): LDS hist -> scan -> fine-bin -> gather.
// Gather decomposition: lane = (g<<3)|q; g = edge slot (8 edges/load-instr),
// q = feature block (8 bf16 = 16B per lane). One uint4 load instruction
// fetches 8 full y-rows (1 KB); up to 4 issued back-to-back (4 KB in
// flight/wave). 3-step shfl_xor butterfly (8/16/32) combines edge slots.
__global__ __launch_bounds__(256) void mega_kernel(
        const int* __restrict__ fpairs, const int* __restrict__ fcur,
        const unsigned short* __restrict__ y,
        const float* __restrict__ bias, float* __restrict__ out) {
    __shared__ int hist[FNODES];
    __shared__ int sc[FNODES];
    __shared__ int lrptr[FNODES + 1];
    __shared__ int lcur[FNODES];
    __shared__ float dl[FNODES];
    __shared__ int lds_scol[CAPF];
    int t = threadIdx.x;
    int b = blockIdx.x;
    int beg = b * CAPF, end = fcur[b];
    if (t < FNODES) hist[t] = 0;
    __syncthreads();
    for (int k = beg + t; k < end; k += 256)
        atomicAdd(&hist[fpairs[k] >> COLBITS], 1);
    __syncthreads();
    if (t < FNODES) sc[t] = hist[t];
    __syncthreads();
    for (int off = 1; off < FNODES; off <<= 1) {
        int v = (t < FNODES && t >= off) ? sc[t - off] : 0;
        __syncthreads();
        if (t < FNODES) sc[t] += v;
        __syncthreads();
    }
    if (t < FNODES) {
        lrptr[t + 1] = sc[t];
        lcur[t] = sc[t] - hist[t];
        dl[t] = (hist[t] > 0) ? rsqrtf((float)hist[t]) : 0.0f;
    }
    if (t == 0) lrptr[0] = 0;
    __syncthreads();
    for (int k = beg + t; k < end; k += 256) {
        int p = fpairs[k];
        int pos = atomicAdd(&lcur[p >> COLBITS], 1);
        lds_scol[pos] = p & COLMASK;
    }
    __syncthreads();
    int wave = t >> 6;
    int lane = t & 63;
    int g = lane >> 3;     // edge slot 0..7
    int q = lane & 7;      // feature block: feats q*8 .. q*8+7
    float bj[8];
    {
        float4 b0 = *(const float4*)(bias + q * 8);
        float4 b1 = *(const float4*)(bias + q * 8 + 4);
        bj[0] = b0.x; bj[1] = b0.y; bj[2] = b0.z; bj[3] = b0.w;
        bj[4] = b1.x; bj[5] = b1.y; bj[6] = b1.z; bj[7] = b1.w;
    }
    for (int ln = wave; ln < FNODES; ln += 4) {
        int s = lrptr[ln], e2 = lrptr[ln + 1];
        float a[8];
#pragma unroll
        for (int i = 0; i < 8; ++i) a[i] = 0.0f;
        for (int k = s; k < e2; k += 32) {
#pragma unroll
            for (int u = 0; u < 4; ++u) {
                int e = k + u * 8 + g;
                if (e < e2) {
                    int c = lds_scol[e];
                    uint4 v = *(const uint4*)(y + (size_t)c * D + q * 8);
                    a[0] += __uint_as_float(v.x << 16);
                    a[1] += __uint_as_float(v.x & 0xffff0000u);
                    a[2] += __uint_as_float(v.y << 16);
                    a[3] += __uint_as_float(v.y & 0xffff0000u);
                    a[4] += __uint_as_float(v.z << 16);
                    a[5] += __uint_as_float(v.z & 0xffff0000u);
                    a[6] += __uint_as_float(v.w << 16);
                    a[7] += __uint_as_float(v.w & 0xffff0000u);
                }
            }
        }
#pragma unroll
        for (int m = 8; m <= 32; m <<= 1) {
#pragma unroll
            for (int i = 0; i < 8; ++i)
                a[i] += __shfl_xor(a[i], m);
        }
        float dv = dl[ln];
        int n = (b << FSHIFT) + ln;
        if (g < 2) {
            int o = g * 4;
            fvec4 r;
            r.x = fmaxf(fmaf(dv, a[o + 0], bj[o + 0]), 0.0f);
            r.y = fmaxf(fmaf(dv, a[o + 1], bj[o + 1]), 0.0f);
            r.z = fmaxf(fmaf(dv, a[o + 2], bj[o + 2]), 0.0f);
            r.w = fmaxf(fmaf(dv, a[o + 3], bj[o + 3]), 0.0f);
            __builtin_nontemporal_store(r, (fvec4*)(out + (size_t)n * D + q * 8 + o));
        }
    }
}

extern "C" void kernel_launch(void* const* d_in, const int* in_sizes, int n_in,
                              void* d_out, int out_size, void* d_ws, size_t ws_size,
                              hipStream_t stream) {
    const float* x    = (const float*)d_in[0];
    const int*   eidx = (const int*)d_in[1];
    const float* W    = (const float*)d_in[2];
    const float* b    = (const float*)d_in[3];
    float* out = (float*)d_out;
    char* ws = (char*)d_ws;

    const int* row = eidx;
    const int* col = eidx + N_EDGES;

    int* fcur   = (int*)(ws + FCUR_OFF);
    int* ccur   = (int*)(ws + CCUR_OFF);
    int* cpairs = (int*)(ws + CPAIRS_OFF);
    int* fpairs = (int*)(ws + FPAIRS_OFF);
    unsigned short* y = (unsigned short*)(ws + Y_OFF);

    initcur_kernel<<<(NFB + 255) / 256, 256, 0, stream>>>(fcur, ccur);
    scatA_kernel<<<NCHUNKA, 256, 0, stream>>>(row, col, ccur, cpairs);
    scatB_kernel<<<NCB * NCHUNKB, 256, 0, stream>>>(cpairs, ccur, fcur, fpairs);
    xform_kernel<<<(N_NODES + 63) / 64, 256, 0, stream>>>(x, W, fpairs, fcur, y);
    mega_kernel<<<NFB, 256, 0, stream>>>(fpairs, fcur, y, b, out);
}